// Round 5
// baseline (142.475 us; speedup 1.0000x reference)
//
#include <hip/hip_runtime.h>
#include <hip/hip_bf16.h>
#include <math.h>

#define NHEADS 8
#define NTOK   1024
#define MTOK   2048

typedef __attribute__((ext_vector_type(8))) short  sh8;
typedef __attribute__((ext_vector_type(8))) __bf16 bf16x8;
typedef __attribute__((ext_vector_type(4))) float  f32x4;

__device__ __forceinline__ short f2bf(float v) {
    return __builtin_bit_cast(short, __float2bfloat16(v));
}
__device__ __forceinline__ float bf2f(short v) {
    return __builtin_bit_cast(float, ((unsigned)(unsigned short)v) << 16);
}
__device__ __forceinline__ f32x4 mfma16(sh8 a, sh8 b, f32x4 c) {
    return __builtin_amdgcn_mfma_f32_16x16x32_bf16(
        __builtin_bit_cast(bf16x8, a), __builtin_bit_cast(bf16x8, b), c, 0, 0, 0);
}
__device__ __forceinline__ void aload16(void* lds, const void* g) {
    __builtin_amdgcn_global_load_lds(
        (const __attribute__((address_space(1))) unsigned int*)g,
        (__attribute__((address_space(3))) unsigned int*)lds, 16, 0, 0);
}

// ---------------- LayerNorm -> bf16 ----------------
__global__ __launch_bounds__(256) void ln_bf16(const float* __restrict__ x,
    const float* __restrict__ g, const float* __restrict__ bta, short* __restrict__ y)
{
    int row = blockIdx.x, t = threadIdx.x;
    const float* xr = x + (size_t)row * 512;
    float2 v = *reinterpret_cast<const float2*>(&xr[t*2]);
    float s = v.x + v.y, ss = v.x*v.x + v.y*v.y;
    #pragma unroll
    for (int m = 1; m < 64; m <<= 1) { s += __shfl_xor(s, m); ss += __shfl_xor(ss, m); }
    __shared__ float red[8];
    int wid = t >> 6, lane = t & 63;
    if (!lane) { red[wid] = s; red[4+wid] = ss; }
    __syncthreads();
    s = red[0]+red[1]+red[2]+red[3]; ss = red[4]+red[5]+red[6]+red[7];
    float mu = s*(1.f/512), var = ss*(1.f/512) - mu*mu, rs = rsqrtf(var + 1e-5f);
    float2 gg = *reinterpret_cast<const float2*>(&g[t*2]);
    float2 bb = *reinterpret_cast<const float2*>(&bta[t*2]);
    short2 o; o.x = f2bf((v.x-mu)*rs*gg.x + bb.x); o.y = f2bf((v.y-mu)*rs*gg.y + bb.y);
    *reinterpret_cast<short2*>(&y[(size_t)row*512 + t*2]) = o;
}

// ---------------- fp32 W[K][N] -> bf16 W^T[N][K] ----------------
__global__ __launch_bounds__(256) void wconv_t(const float* __restrict__ W,
    short* __restrict__ WT, int K, int N)
{
    __shared__ float t[32][33];
    int bn = blockIdx.x * 32, bk = blockIdx.y * 32;
    int c = threadIdx.x & 31, r8 = threadIdx.x >> 5;
    #pragma unroll
    for (int i = 0; i < 4; ++i) {
        int r = r8 + i*8;
        t[r][c] = W[(size_t)(bk + r)*N + bn + c];
    }
    __syncthreads();
    #pragma unroll
    for (int i = 0; i < 4; ++i) {
        int r = r8 + i*8;
        WT[(size_t)(bn + r)*K + bk + c] = f2bf(t[c][r]);
    }
}

// ---------------- o[i] = a[i] + bias[i % 512]  (f32, vectorized) ----------------
__global__ __launch_bounds__(256) void addbias_f32(const float* __restrict__ a,
    const float* __restrict__ bias, float* __restrict__ o)
{
    int e = (blockIdx.x*256 + threadIdx.x)*4;
    float4 av = *reinterpret_cast<const float4*>(a + e);
    float4 bv = *reinterpret_cast<const float4*>(bias + (e & 511));
    float4 ov = {av.x+bv.x, av.y+bv.y, av.z+bv.z, av.w+bv.w};
    *reinterpret_cast<float4*>(o + e) = ov;
}

// ---------------- pack padding mask into per-(row, 64-tile) bit masks ----------
__global__ __launch_bounds__(256) void mask_pack(const unsigned char* __restrict__ m,
    unsigned long long* __restrict__ mb)
{
    int gw = blockIdx.x*4 + (threadIdx.x >> 6);   // 32768 waves
    int row = gw >> 4, jt = gw & 15, j = threadIdx.x & 63;
    unsigned char v = m[(size_t)row*NTOK + jt*64 + j];
    unsigned long long bits = __ballot(v != 0);
    if (j == 0) mb[(size_t)row*16 + jt] = bits;
}

// ---------------- bf16 MFMA GEMM, 64x64 tile, BK=64, 2-phase dbuf --------------
// QSC: multiply (acc+bias) by 0.125 for cols < 512 (folds attention scale into q)
template<int EPI, bool OUTBF, bool BIAS_ROW, int SPLITK, bool QSC>
__global__ __launch_bounds__(256) void gemm64(
    const short* __restrict__ A, const short* __restrict__ BT,
    const float* __restrict__ bias, void* __restrict__ Cout,
    int M, int N, int K, int nbx)
{
    __shared__ sh8 As8[2][512];
    __shared__ sh8 Bs8[2][512];
    int tid = threadIdx.x;
    int w = tid >> 6, lane = tid & 63, lr = lane & 15, lg = lane >> 4;
    int wr = w >> 1, wc = w & 1;
    int cpx = gridDim.x >> 3;
    int swz = (blockIdx.x & 7)*cpx + (blockIdx.x >> 3);
    int bx = swz % nbx, by = swz / nbx;
    int bm0 = by*64, bn0 = bx*64;
    int kbeg = (K / SPLITK) * blockIdx.z;
    int nt = (K / SPLITK) / 64;

    f32x4 zero = {0.f,0.f,0.f,0.f};
    f32x4 acc[2][2];
    #pragma unroll
    for (int m = 0; m < 2; ++m)
        #pragma unroll
        for (int n = 0; n < 2; ++n) acc[m][n] = zero;

    #define STAGE(buf, k0) { \
        _Pragma("unroll") \
        for (int it = 0; it < 2; ++it) { \
            int s = tid + it*256; \
            int r = s >> 3, g = s & 7; \
            int ksw = (k0) + ((g ^ (r & 7)) << 3); \
            aload16(&As8[buf][s], A  + (size_t)(bm0 + r)*K + ksw); \
            aload16(&Bs8[buf][s], BT + (size_t)(bn0 + r)*K + ksw); \
        } }

    STAGE(0, kbeg)
    asm volatile("s_waitcnt vmcnt(0)" ::: "memory");
    __syncthreads();

    for (int t = 0; t < nt; ++t) {
        int buf = t & 1;
        if (t + 1 < nt) STAGE(buf ^ 1, kbeg + (t+1)*64)
        sh8 af[2][2], bfv[2][2];
        #pragma unroll
        for (int m = 0; m < 2; ++m) {
            int R = wr*32 + m*16 + lr;
            #pragma unroll
            for (int s = 0; s < 2; ++s) af[m][s] = As8[buf][R*8 + ((s*4+lg) ^ (R & 7))];
        }
        #pragma unroll
        for (int n = 0; n < 2; ++n) {
            int R = wc*32 + n*16 + lr;
            #pragma unroll
            for (int s = 0; s < 2; ++s) bfv[n][s] = Bs8[buf][R*8 + ((s*4+lg) ^ (R & 7))];
        }
        #pragma unroll
        for (int m = 0; m < 2; ++m)
            #pragma unroll
            for (int n = 0; n < 2; ++n)
                #pragma unroll
                for (int s = 0; s < 2; ++s)
                    acc[m][n] = mfma16(af[m][s], bfv[n][s], acc[m][n]);
        asm volatile("s_waitcnt vmcnt(0)" ::: "memory");
        __syncthreads();
    }
    #undef STAGE

    #pragma unroll
    for (int m = 0; m < 2; ++m) {
        #pragma unroll
        for (int n = 0; n < 2; ++n) {
            #pragma unroll
            for (int r = 0; r < 4; ++r) {
                int row = bm0 + wr*32 + m*16 + lg*4 + r;
                int col = bn0 + wc*32 + n*16 + lr;
                if (EPI == 3) {
                    atomicAdd((float*)Cout + (size_t)row*N + col, acc[m][n][r]);
                } else {
                    float v = acc[m][n][r] + (BIAS_ROW ? bias[row] : bias[col]);
                    if (QSC && col < 512) v *= 0.125f;
                    if (EPI == 2) v = 0.5f * v * (1.0f + erff(v * 0.70710678f));
                    if (OUTBF) ((short*)Cout)[(size_t)row*N + col] = f2bf(v);
                    else       ((float*)Cout)[(size_t)row*N + col] = v;
                }
            }
        }
    }
}

// ---------------- barrier-free register-KV flash attention, KV-split x4 -------
// qk: [2048 tok][1024] bf16 (q pre-scaled);  vt: [512 vd][2048 tok]
// Each wave: 16 q rows, 4 KV tiles. Partials (unnormalized bf16 O, f32 m/l) -> ws.
__global__ __launch_bounds__(256) void attn_reg(
    const short* __restrict__ qk, const short* __restrict__ vt,
    const float* __restrict__ coords, const unsigned long long* __restrict__ mb64,
    const float* __restrict__ w_edge, short* __restrict__ Op, float* __restrict__ ml)
{
    __shared__ sh8 Ps8[4][128];   // per-wave P tile [16 q][64 k], swizzled

    int cpx = gridDim.x >> 3;
    int swz = (blockIdx.x & 7)*cpx + (blockIdx.x >> 3);   // 1024 blocks, bijective
    int w = threadIdx.x >> 6, lane = threadIdx.x & 63;
    int lr = lane & 15, lg = lane >> 4;
    int gw = swz*4 + w;
    int qt = gw & 63;          // q tile of 16 rows
    int h  = (gw >> 6) & 7;
    int b  = (gw >> 9) & 1;
    int ks = (gw >> 10) & 3;   // KV split 0..3

    const int qrow0 = b*NTOK + qt*16;

    // Q fragments (A operand: row = lr, d = s*32 + lg*8..+7)
    sh8 qf[2];
    #pragma unroll
    for (int s = 0; s < 2; ++s)
        qf[s] = *reinterpret_cast<const sh8*>(qk + (size_t)(qrow0 + lr)*1024 + h*64 + s*32 + lg*8);

    float qx[4], qy[4];
    #pragma unroll
    for (int r = 0; r < 4; ++r) {
        float2 c = *reinterpret_cast<const float2*>(&coords[(size_t)(qrow0 + lg*4 + r)*2]);
        qx[r] = c.x; qy[r] = c.y;
    }
    float we2 = w_edge[2*NHEADS + h];

    float m_i[4], l_i[4];
    f32x4 zero = {0.f,0.f,0.f,0.f};
    f32x4 accO[4];
    #pragma unroll
    for (int r = 0; r < 4; ++r) { m_i[r] = -1e30f; l_i[r] = 0.f; }
    #pragma unroll
    for (int n = 0; n < 4; ++n) accO[n] = zero;

    const short* kb = qk + 512 + h*64;
    const short* vb = vt + (size_t)h*64*2048 + b*NTOK;

    for (int t = 0; t < 4; ++t) {
        int jt = ks*4 + t;
        int k0 = b*NTOK + jt*64;

        // K fragments (B operand: col k = n*16+lr, d slices by lg)
        sh8 kf0[4], kf1[4];
        #pragma unroll
        for (int n = 0; n < 4; ++n) {
            const short* kr = kb + (size_t)(k0 + n*16 + lr)*1024 + lg*8;
            kf0[n] = *reinterpret_cast<const sh8*>(kr);
            kf1[n] = *reinterpret_cast<const sh8*>(kr + 32);
        }
        // V fragments (B operand for PV: col d = n*16+lr, k slices by lg)
        sh8 vf0[4], vf1[4];
        #pragma unroll
        for (int n = 0; n < 4; ++n) {
            const short* vr = vb + (size_t)(n*16 + lr)*2048 + jt*64 + lg*8;
            vf0[n] = *reinterpret_cast<const sh8*>(vr);
            vf1[n] = *reinterpret_cast<const sh8*>(vr + 32);
        }
        // k coords + mask bits (4 x 8B broadcast loads)
        float2 kc[4];
        #pragma unroll
        for (int n = 0; n < 4; ++n)
            kc[n] = *reinterpret_cast<const float2*>(&coords[(size_t)(k0 + n*16 + lr)*2]);
        unsigned long long mrow[4];
        #pragma unroll
        for (int r = 0; r < 4; ++r)
            mrow[r] = mb64[(size_t)(qrow0 + lg*4 + r)*16 + jt];

        // S = Q K^T (q pre-scaled by 0.125)
        f32x4 Sv[4];
        __builtin_amdgcn_s_setprio(1);
        #pragma unroll
        for (int n = 0; n < 4; ++n)
            Sv[n] = mfma16(qf[1], kf1[n], mfma16(qf[0], kf0[n], zero));
        __builtin_amdgcn_s_setprio(0);

        // radial bias + mask
        #pragma unroll
        for (int n = 0; n < 4; ++n) {
            #pragma unroll
            for (int r = 0; r < 4; ++r) {
                float dx = qx[r] - kc[n].x, dy = qy[r] - kc[n].y;
                float rn = sqrtf(dx*dx + dy*dy);
                float sv = Sv[n][r] + rn*we2;
                Sv[n][r] = ((mrow[r] >> (n*16 + lr)) & 1ull) ? -1e9f : sv;
            }
        }

        // online softmax (row = 16 lanes sharing lg)
        #pragma unroll
        for (int r = 0; r < 4; ++r) {
            float mx = fmaxf(fmaxf(Sv[0][r], Sv[1][r]), fmaxf(Sv[2][r], Sv[3][r]));
            #pragma unroll
            for (int msk = 1; msk < 16; msk <<= 1) mx = fmaxf(mx, __shfl_xor(mx, msk));
            float mnew = fmaxf(m_i[r], mx);
            float f = __expf(m_i[r] - mnew);
            m_i[r] = mnew;
            float rs = 0.f;
            #pragma unroll
            for (int n = 0; n < 4; ++n) { float p = __expf(Sv[n][r] - mnew); Sv[n][r] = p; rs += p; }
            #pragma unroll
            for (int msk = 1; msk < 16; msk <<= 1) rs += __shfl_xor(rs, msk);
            l_i[r] = l_i[r]*f + rs;
            #pragma unroll
            for (int n = 0; n < 4; ++n) accO[n][r] *= f;
        }

        // P -> wave-private LDS (swizzled), reload as A fragments
        short* Pw = (short*)&Ps8[w][0];
        #pragma unroll
        for (int r = 0; r < 4; ++r) {
            int q = lg*4 + r;
            #pragma unroll
            for (int n = 0; n < 4; ++n) {
                int k = n*16 + lr;
                Pw[q*64 + (((k>>3) ^ (q&7)) << 3) + (k&7)] = f2bf(Sv[n][r]);
            }
        }
        sh8 pa[2];
        #pragma unroll
        for (int s = 0; s < 2; ++s)
            pa[s] = Ps8[w][lr*8 + ((s*4 + lg) ^ (lr & 7))];

        // PV
        __builtin_amdgcn_s_setprio(1);
        #pragma unroll
        for (int n = 0; n < 4; ++n)
            accO[n] = mfma16(pa[1], vf1[n], mfma16(pa[0], vf0[n], accO[n]));
        __builtin_amdgcn_s_setprio(0);
    }

    // partials: unnormalized bf16 O + (m, l)
    #pragma unroll
    for (int r = 0; r < 4; ++r) {
        size_t row = (size_t)(ks*MTOK + qrow0 + lg*4 + r);
        #pragma unroll
        for (int n = 0; n < 4; ++n)
            Op[row*512 + h*64 + n*16 + lr] = f2bf(accO[n][r]);
        if (lr == 0) {
            ml[(row*NHEADS + h)*2 + 0] = m_i[r];
            ml[(row*NHEADS + h)*2 + 1] = l_i[r];
        }
    }
}

// ---------------- combine 4 KV-split partials -> bf16 O ----------------
__global__ __launch_bounds__(256) void attn_combine(const short* __restrict__ Op,
    const float* __restrict__ ml, short* __restrict__ ob)
{
    int idx = blockIdx.x*256 + threadIdx.x;     // MTOK*128 threads
    int tok = idx >> 7, dd = (idx & 127) * 4;
    int h = dd >> 6;
    float m[4], l[4];
    #pragma unroll
    for (int s = 0; s < 4; ++s) {
        m[s] = ml[(((size_t)s*MTOK + tok)*NHEADS + h)*2 + 0];
        l[s] = ml[(((size_t)s*MTOK + tok)*NHEADS + h)*2 + 1];
    }
    float mm = fmaxf(fmaxf(m[0], m[1]), fmaxf(m[2], m[3]));
    float wsum = 0.f, acc0 = 0.f, acc1 = 0.f, acc2 = 0.f, acc3 = 0.f;
    #pragma unroll
    for (int s = 0; s < 4; ++s) {
        float wv = __expf(m[s] - mm);
        wsum += wv * l[s];
        short4 p = *reinterpret_cast<const short4*>(&Op[((size_t)s*MTOK + tok)*512 + dd]);
        acc0 += bf2f(p.x)*wv; acc1 += bf2f(p.y)*wv;
        acc2 += bf2f(p.z)*wv; acc3 += bf2f(p.w)*wv;
    }
    float inv = 1.f / wsum;
    short4 o;
    o.x = f2bf(acc0*inv); o.y = f2bf(acc1*inv);
    o.z = f2bf(acc2*inv); o.w = f2bf(acc3*inv);
    *reinterpret_cast<short4*>(&ob[(size_t)tok*512 + dd]) = o;
}

// -------------------------------------------------------------------------------
extern "C" void kernel_launch(void* const* d_in, const int* in_sizes, int n_in,
                              void* d_out, int out_size, void* d_ws, size_t ws_size,
                              hipStream_t stream)
{
    const float* x      = (const float*)d_in[0];
    const float* coords = (const float*)d_in[1];
    const unsigned char* mask = (const unsigned char*)d_in[2];
    const float* ln1_g = (const float*)d_in[3];
    const float* ln1_b = (const float*)d_in[4];
    const float* w_qkv = (const float*)d_in[5];
    const float* b_qkv = (const float*)d_in[6];
    const float* w_edge= (const float*)d_in[7];
    const float* w_out = (const float*)d_in[8];
    const float* b_out = (const float*)d_in[9];
    const float* ln2_g = (const float*)d_in[10];
    const float* ln2_b = (const float*)d_in[11];
    const float* w1    = (const float*)d_in[12];
    const float* b1    = (const float*)d_in[13];
    const float* w2    = (const float*)d_in[14];
    const float* b2    = (const float*)d_in[15];
    float* out = (float*)d_out;

    char* W = (char*)d_ws;
    const size_t MB = 1024*1024;
    // liveness-planned layout (max 23.25 MB)
    float* x1    = (float*)(W);                    // [0,4M) f32
    short* qk    = (short*)(W + 4*MB);             // [4M,8M)
    short* vtb   = (short*)(W + 8*MB);             // [8M,10M)
    short* woutT = (short*)(W + 10*MB);            // [10M,10.5M)
    short* xln   = (short*)(W + 10*MB + 512*1024); // [10.5M,12.5M)  (later y)
    short* wqkvT = (short*)(W + 12*MB + 512*1024); // [12.5M,14M)
    short* Opart = (short*)(W + 14*MB + 512*1024); // [14.5M,22.5M) bf16 4x2048x512
    float* mlp   = (float*)(W + 22*MB + 512*1024); // [22.5M,23M)
    unsigned long long* mb64 = (unsigned long long*)(W + 23*MB); // [23M,23.25M)
    short* ob    = (short*)(W + 6*MB);             // [6M,8M)   (qk dead after attn)
    short* y     = xln;
    short* w1T   = (short*)(W + 4*MB);             // [4M,6M)   (qk dead)
    short* w2T   = (short*)(W + 8*MB);             // [8M,10M)  (vtb dead)
    short* hid   = (short*)(W + 14*MB + 512*1024); // [14.5M,22.5M) (Opart dead)

    // ---- phase 1 ----
    mask_pack<<<dim3(8192,1,1), 256, 0, stream>>>(mask, mb64);
    wconv_t<<<dim3(1536/32, 512/32), 256, 0, stream>>>(w_qkv, wqkvT, 512, 1536);
    wconv_t<<<dim3(512/32, 512/32), 256, 0, stream>>>(w_out, woutT, 512, 512);
    ln_bf16<<<MTOK, 256, 0, stream>>>(x, ln1_g, ln1_b, xln);
    gemm64<0,true,false,1,true><<<dim3(512,1,1), 256, 0, stream>>>(
        xln, wqkvT, b_qkv, qk, MTOK, 1024, 512, 16);
    gemm64<0,true,true,1,false><<<dim3(256,1,1), 256, 0, stream>>>(
        wqkvT + (size_t)1024*512, xln, b_qkv + 1024, vtb, 512, MTOK, 512, 32);
    attn_reg<<<dim3(1024,1,1), 256, 0, stream>>>(qk, vtb, coords, mb64, w_edge, Opart, mlp);
    attn_combine<<<dim3(1024,1,1), 256, 0, stream>>>(Opart, mlp, ob);
    addbias_f32<<<1024, 256, 0, stream>>>(x, b_out, x1);
    gemm64<3,false,false,2,false><<<dim3(256,1,2), 256, 0, stream>>>(
        ob, woutT, nullptr, x1, MTOK, 512, 512, 8);
    // ---- phase 2 ----
    wconv_t<<<dim3(2048/32, 512/32), 256, 0, stream>>>(w1, w1T, 512, 2048);
    wconv_t<<<dim3(512/32, 2048/32), 256, 0, stream>>>(w2, w2T, 2048, 512);
    ln_bf16<<<MTOK, 256, 0, stream>>>(x1, ln2_g, ln2_b, y);
    gemm64<2,true,false,1,false><<<dim3(1024,1,1), 256, 0, stream>>>(
        y, w1T, b1, hid, MTOK, 2048, 512, 32);
    addbias_f32<<<1024, 256, 0, stream>>>(x1, b2, out);
    gemm64<3,false,false,4,false><<<dim3(256,1,4), 256, 0, stream>>>(
        hid, w2T, nullptr, out, MTOK, 512, 2048, 8);
}

// Round 6
// 134.446 us; speedup vs baseline: 1.0597x; 1.0597x over previous
//
#include <hip/hip_runtime.h>
#include <hip/hip_bf16.h>
#include <math.h>

#define NHEADS 8
#define NTOK   1024
#define MTOK   2048

typedef __attribute__((ext_vector_type(8))) short  sh8;
typedef __attribute__((ext_vector_type(8))) __bf16 bf16x8;
typedef __attribute__((ext_vector_type(4))) float  f32x4;

__device__ __forceinline__ short f2bf(float v) {
    return __builtin_bit_cast(short, __float2bfloat16(v));
}
__device__ __forceinline__ float bf2f(short v) {
    return __builtin_bit_cast(float, ((unsigned)(unsigned short)v) << 16);
}
__device__ __forceinline__ f32x4 mfma16(sh8 a, sh8 b, f32x4 c) {
    return __builtin_amdgcn_mfma_f32_16x16x32_bf16(
        __builtin_bit_cast(bf16x8, a), __builtin_bit_cast(bf16x8, b), c, 0, 0, 0);
}
__device__ __forceinline__ void aload16(void* lds, const void* g) {
    __builtin_amdgcn_global_load_lds(
        (const __attribute__((address_space(1))) unsigned int*)g,
        (__attribute__((address_space(3))) unsigned int*)lds, 16, 0, 0);
}

// ---------------- LayerNorm -> bf16 ----------------
__global__ __launch_bounds__(256) void ln_bf16(const float* __restrict__ x,
    const float* __restrict__ g, const float* __restrict__ bta, short* __restrict__ y)
{
    int row = blockIdx.x, t = threadIdx.x;
    const float* xr = x + (size_t)row * 512;
    float2 v = *reinterpret_cast<const float2*>(&xr[t*2]);
    float s = v.x + v.y, ss = v.x*v.x + v.y*v.y;
    #pragma unroll
    for (int m = 1; m < 64; m <<= 1) { s += __shfl_xor(s, m); ss += __shfl_xor(ss, m); }
    __shared__ float red[8];
    int wid = t >> 6, lane = t & 63;
    if (!lane) { red[wid] = s; red[4+wid] = ss; }
    __syncthreads();
    s = red[0]+red[1]+red[2]+red[3]; ss = red[4]+red[5]+red[6]+red[7];
    float mu = s*(1.f/512), var = ss*(1.f/512) - mu*mu, rs = rsqrtf(var + 1e-5f);
    float2 gg = *reinterpret_cast<const float2*>(&g[t*2]);
    float2 bb = *reinterpret_cast<const float2*>(&bta[t*2]);
    short2 o; o.x = f2bf((v.x-mu)*rs*gg.x + bb.x); o.y = f2bf((v.y-mu)*rs*gg.y + bb.y);
    *reinterpret_cast<short2*>(&y[(size_t)row*512 + t*2]) = o;
}

// ---------------- fp32 W[K][N] -> bf16 W^T[N][K] ----------------
__global__ __launch_bounds__(256) void wconv_t(const float* __restrict__ W,
    short* __restrict__ WT, int K, int N)
{
    __shared__ float t[32][33];
    int bn = blockIdx.x * 32, bk = blockIdx.y * 32;
    int c = threadIdx.x & 31, r8 = threadIdx.x >> 5;
    #pragma unroll
    for (int i = 0; i < 4; ++i) {
        int r = r8 + i*8;
        t[r][c] = W[(size_t)(bk + r)*N + bn + c];
    }
    __syncthreads();
    #pragma unroll
    for (int i = 0; i < 4; ++i) {
        int r = r8 + i*8;
        WT[(size_t)(bn + r)*K + bk + c] = f2bf(t[c][r]);
    }
}

// ---------------- o[i] = a[i] + bias[i % 512]  (f32, vectorized) ----------------
__global__ __launch_bounds__(256) void addbias_f32(const float* __restrict__ a,
    const float* __restrict__ bias, float* __restrict__ o)
{
    int e = (blockIdx.x*256 + threadIdx.x)*4;
    float4 av = *reinterpret_cast<const float4*>(a + e);
    float4 bv = *reinterpret_cast<const float4*>(bias + (e & 511));
    float4 ov = {av.x+bv.x, av.y+bv.y, av.z+bv.z, av.w+bv.w};
    *reinterpret_cast<float4*>(o + e) = ov;
}

// ---------------- pack padding mask into per-(row, 64-tile) bit masks ----------
__global__ __launch_bounds__(256) void mask_pack(const unsigned char* __restrict__ m,
    unsigned long long* __restrict__ mb)
{
    int gw = blockIdx.x*4 + (threadIdx.x >> 6);   // 32768 waves
    int row = gw >> 4, jt = gw & 15, j = threadIdx.x & 63;
    unsigned char v = m[(size_t)row*NTOK + jt*64 + j];
    unsigned long long bits = __ballot(v != 0);
    if (j == 0) mb[(size_t)row*16 + jt] = bits;
}

// ---------------- bf16 MFMA GEMM, 64x64 tile, BK=64, 3-stage counted-vmcnt ----
// EPI: 0 bias; 2 bias+gelu; 3 split-K atomicAdd into f32.  NT = K-steps (compile-time)
template<int EPI, bool OUTBF, bool BIAS_ROW, int SPLITK, bool QSC, int NT>
__global__ __launch_bounds__(256) void gemm64(
    const short* __restrict__ A, const short* __restrict__ BT,
    const float* __restrict__ bias, void* __restrict__ Cout,
    int M, int N, int K, int nbx)
{
    __shared__ sh8 As8[3][512];
    __shared__ sh8 Bs8[3][512];
    int tid = threadIdx.x;
    int w = tid >> 6, lane = tid & 63, lr = lane & 15, lg = lane >> 4;
    int wr = w >> 1, wc = w & 1;
    int cpx = gridDim.x >> 3;
    int swz = (blockIdx.x & 7)*cpx + (blockIdx.x >> 3);
    int bx = swz % nbx, by = swz / nbx;
    int bm0 = by*64, bn0 = bx*64;
    int kbeg = (K / SPLITK) * blockIdx.z;

    f32x4 zero = {0.f,0.f,0.f,0.f};
    f32x4 acc[2][2];
    #pragma unroll
    for (int m = 0; m < 2; ++m)
        #pragma unroll
        for (int n = 0; n < 2; ++n) acc[m][n] = zero;

    #define STAGE(buf, k0) { \
        _Pragma("unroll") \
        for (int it = 0; it < 2; ++it) { \
            int s = tid + it*256; \
            int r = s >> 3, g = s & 7; \
            int ksw = (k0) + ((g ^ (r & 7)) << 3); \
            aload16(&As8[buf][s], A  + (size_t)(bm0 + r)*K + ksw); \
            aload16(&Bs8[buf][s], BT + (size_t)(bn0 + r)*K + ksw); \
        } }

    STAGE(0, kbeg)
    if (NT > 1) STAGE(1, kbeg + 64)

    #pragma unroll
    for (int t = 0; t < NT; ++t) {
        // wait for stage t's 4 loads; leave stage t+1's 4 in flight
        if (t + 1 < NT) asm volatile("s_waitcnt vmcnt(4)" ::: "memory");
        else            asm volatile("s_waitcnt vmcnt(0)" ::: "memory");
        __syncthreads();
        int buf = t % 3;
        sh8 af[2][2], bfv[2][2];
        #pragma unroll
        for (int m = 0; m < 2; ++m) {
            int R = wr*32 + m*16 + lr;
            #pragma unroll
            for (int s = 0; s < 2; ++s) af[m][s] = As8[buf][R*8 + ((s*4+lg) ^ (R & 7))];
        }
        #pragma unroll
        for (int n = 0; n < 2; ++n) {
            int R = wc*32 + n*16 + lr;
            #pragma unroll
            for (int s = 0; s < 2; ++s) bfv[n][s] = Bs8[buf][R*8 + ((s*4+lg) ^ (R & 7))];
        }
        if (t + 2 < NT) STAGE((t+2)%3, kbeg + (t+2)*64)
        #pragma unroll
        for (int m = 0; m < 2; ++m)
            #pragma unroll
            for (int n = 0; n < 2; ++n)
                #pragma unroll
                for (int s = 0; s < 2; ++s)
                    acc[m][n] = mfma16(af[m][s], bfv[n][s], acc[m][n]);
        // ensure this wave's ds_reads completed before next-iter barrier permits overwrite
        asm volatile("s_waitcnt lgkmcnt(0)" ::: "memory");
    }
    #undef STAGE

    #pragma unroll
    for (int m = 0; m < 2; ++m) {
        #pragma unroll
        for (int n = 0; n < 2; ++n) {
            #pragma unroll
            for (int r = 0; r < 4; ++r) {
                int row = bm0 + wr*32 + m*16 + lg*4 + r;
                int col = bn0 + wc*32 + n*16 + lr;
                if (EPI == 3) {
                    atomicAdd((float*)Cout + (size_t)row*N + col, acc[m][n][r]);
                } else {
                    float v = acc[m][n][r] + (BIAS_ROW ? bias[row] : bias[col]);
                    if (QSC && col < 512) v *= 0.125f;
                    if (EPI == 2) v = 0.5f * v * (1.0f + erff(v * 0.70710678f));
                    if (OUTBF) ((short*)Cout)[(size_t)row*N + col] = f2bf(v);
                    else       ((float*)Cout)[(size_t)row*N + col] = v;
                }
            }
        }
    }
}

// ---------------- barrier-free register-KV flash attention, KV-split x2 -------
// 2 KV tiles (128 cols) per iteration; lane-local l accumulation (no in-loop sum shfl)
__global__ __launch_bounds__(256) void attn_reg(
    const short* __restrict__ qk, const short* __restrict__ vt,
    const float* __restrict__ coords, const unsigned long long* __restrict__ mb64,
    const float* __restrict__ w_edge, short* __restrict__ Op, float* __restrict__ ml)
{
    __shared__ sh8 Ps8[4][256];   // per-wave P tile [16 q][128 k], 16 slots/row, swizzled

    int swz = (blockIdx.x & 7)*64 + (blockIdx.x >> 3);   // 512 blocks, bijective
    int w = threadIdx.x >> 6, lane = threadIdx.x & 63;
    int lr = lane & 15, lg = lane >> 4;
    int gw = swz*4 + w;        // 2048 waves
    int qt = gw & 63;
    int h  = (gw >> 6) & 7;
    int b  = (gw >> 9) & 1;
    int ks = gw >> 10;         // KV split 0/1

    const int qrow0 = b*NTOK + qt*16;

    sh8 qf[2];
    #pragma unroll
    for (int s = 0; s < 2; ++s)
        qf[s] = *reinterpret_cast<const sh8*>(qk + (size_t)(qrow0 + lr)*1024 + h*64 + s*32 + lg*8);

    float qx[4], qy[4];
    #pragma unroll
    for (int r = 0; r < 4; ++r) {
        float2 c = *reinterpret_cast<const float2*>(&coords[(size_t)(qrow0 + lg*4 + r)*2]);
        qx[r] = c.x; qy[r] = c.y;
    }
    float we2 = w_edge[2*NHEADS + h];

    float m_i[4], l_lane[4];
    f32x4 zero = {0.f,0.f,0.f,0.f};
    f32x4 accO[4];
    #pragma unroll
    for (int r = 0; r < 4; ++r) { m_i[r] = -1e30f; l_lane[r] = 0.f; }
    #pragma unroll
    for (int n = 0; n < 4; ++n) accO[n] = zero;

    const short* kb = qk + 512 + h*64;
    const short* vb = vt + (size_t)h*64*2048 + b*NTOK;

    for (int it = 0; it < 4; ++it) {
        int jt0 = ks*8 + it*2;        // two tiles: jt0, jt0+1
        int k0 = b*NTOK + jt0*64;

        // K fragments for both tiles
        sh8 kf0[2][4], kf1[2][4];
        #pragma unroll
        for (int t2 = 0; t2 < 2; ++t2)
            #pragma unroll
            for (int n = 0; n < 4; ++n) {
                const short* kr = kb + (size_t)(k0 + t2*64 + n*16 + lr)*1024 + lg*8;
                kf0[t2][n] = *reinterpret_cast<const sh8*>(kr);
                kf1[t2][n] = *reinterpret_cast<const sh8*>(kr + 32);
            }
        // coords + mask bits (16B loads, jt0 even)
        float2 kc[2][4];
        #pragma unroll
        for (int t2 = 0; t2 < 2; ++t2)
            #pragma unroll
            for (int n = 0; n < 4; ++n)
                kc[t2][n] = *reinterpret_cast<const float2*>(&coords[(size_t)(k0 + t2*64 + n*16 + lr)*2]);
        ulonglong2 mrow[4];
        #pragma unroll
        for (int r = 0; r < 4; ++r)
            mrow[r] = *reinterpret_cast<const ulonglong2*>(&mb64[(size_t)(qrow0 + lg*4 + r)*16 + jt0]);

        // S = Q K^T for 128 cols
        f32x4 Sv[2][4];
        #pragma unroll
        for (int t2 = 0; t2 < 2; ++t2)
            #pragma unroll
            for (int n = 0; n < 4; ++n)
                Sv[t2][n] = mfma16(qf[1], kf1[t2][n], mfma16(qf[0], kf0[t2][n], zero));

        // V fragments (independent of softmax -> hides under VALU chain)
        sh8 vf[4][4];
        #pragma unroll
        for (int s = 0; s < 4; ++s)
            #pragma unroll
            for (int n = 0; n < 4; ++n)
                vf[s][n] = *reinterpret_cast<const sh8*>(
                    vb + (size_t)(n*16 + lr)*2048 + jt0*64 + s*32 + lg*8);

        // radial bias + mask
        #pragma unroll
        for (int t2 = 0; t2 < 2; ++t2) {
            #pragma unroll
            for (int n = 0; n < 4; ++n) {
                unsigned long long mw;
                #pragma unroll
                for (int r = 0; r < 4; ++r) {
                    mw = t2 ? mrow[r].y : mrow[r].x;
                    float dx = qx[r] - kc[t2][n].x, dy = qy[r] - kc[t2][n].y;
                    float rn = sqrtf(dx*dx + dy*dy);
                    float sv = Sv[t2][n][r] + rn*we2;
                    Sv[t2][n][r] = ((mw >> (n*16 + lr)) & 1ull) ? -1e9f : sv;
                }
            }
        }

        // online softmax across 128 cols (one reduce + one rescale)
        #pragma unroll
        for (int r = 0; r < 4; ++r) {
            float mx = -1e30f;
            #pragma unroll
            for (int t2 = 0; t2 < 2; ++t2)
                #pragma unroll
                for (int n = 0; n < 4; ++n) mx = fmaxf(mx, Sv[t2][n][r]);
            #pragma unroll
            for (int msk = 1; msk < 16; msk <<= 1) mx = fmaxf(mx, __shfl_xor(mx, msk));
            float mnew = fmaxf(m_i[r], mx);
            float f = __expf(m_i[r] - mnew);
            m_i[r] = mnew;
            float rs = 0.f;
            #pragma unroll
            for (int t2 = 0; t2 < 2; ++t2)
                #pragma unroll
                for (int n = 0; n < 4; ++n) {
                    float p = __expf(Sv[t2][n][r] - mnew);
                    Sv[t2][n][r] = p; rs += p;
                }
            l_lane[r] = l_lane[r]*f + rs;     // lane-local; reduced once at end
            #pragma unroll
            for (int n = 0; n < 4; ++n) accO[n][r] *= f;
        }

        // P -> wave-private LDS (swizzled: 16 slots/row, slot ^= q&7)
        short* Pw = (short*)&Ps8[w][0];
        #pragma unroll
        for (int r = 0; r < 4; ++r) {
            int q = lg*4 + r;
            #pragma unroll
            for (int t2 = 0; t2 < 2; ++t2)
                #pragma unroll
                for (int n = 0; n < 4; ++n) {
                    int k = t2*64 + n*16 + lr;
                    Pw[q*128 + (((k>>3) ^ (q&7)) << 3) + (k&7)] = f2bf(Sv[t2][n][r]);
                }
        }
        sh8 pa[4];
        #pragma unroll
        for (int s = 0; s < 4; ++s)
            pa[s] = Ps8[w][lr*16 + ((s*4 + lg) ^ (lr & 7))];

        // PV over 128-k
        #pragma unroll
        for (int n = 0; n < 4; ++n) {
            f32x4 c = accO[n];
            #pragma unroll
            for (int s = 0; s < 4; ++s) c = mfma16(pa[s], vf[s][n], c);
            accO[n] = c;
        }
    }

    // reduce l once
    #pragma unroll
    for (int r = 0; r < 4; ++r) {
        float ls = l_lane[r];
        #pragma unroll
        for (int msk = 1; msk < 16; msk <<= 1) ls += __shfl_xor(ls, msk);
        l_lane[r] = ls;
    }

    // partials: unnormalized bf16 O + (m, l)
    #pragma unroll
    for (int r = 0; r < 4; ++r) {
        size_t row = (size_t)(ks*MTOK + qrow0 + lg*4 + r);
        #pragma unroll
        for (int n = 0; n < 4; ++n)
            Op[row*512 + h*64 + n*16 + lr] = f2bf(accO[n][r]);
        if (lr == 0) {
            ml[(row*NHEADS + h)*2 + 0] = m_i[r];
            ml[(row*NHEADS + h)*2 + 1] = l_lane[r];
        }
    }
}

// ---------------- combine 2 KV-split partials -> bf16 O ----------------
__global__ __launch_bounds__(256) void attn_combine(const short* __restrict__ Op,
    const float* __restrict__ ml, short* __restrict__ ob)
{
    int idx = blockIdx.x*256 + threadIdx.x;     // MTOK*128 threads
    int tok = idx >> 7, dd = (idx & 127) * 4;
    int h = dd >> 6;
    float m0 = ml[((size_t)tok*NHEADS + h)*2 + 0];
    float l0 = ml[((size_t)tok*NHEADS + h)*2 + 1];
    float m1 = ml[(((size_t)MTOK + tok)*NHEADS + h)*2 + 0];
    float l1 = ml[(((size_t)MTOK + tok)*NHEADS + h)*2 + 1];
    float mm = fmaxf(m0, m1);
    float w0 = __expf(m0 - mm), w1 = __expf(m1 - mm);
    float inv = 1.f / (w0*l0 + w1*l1);
    short4 a = *reinterpret_cast<const short4*>(&Op[(size_t)tok*512 + dd]);
    short4 c = *reinterpret_cast<const short4*>(&Op[((size_t)MTOK + tok)*512 + dd]);
    short4 o;
    o.x = f2bf((bf2f(a.x)*w0 + bf2f(c.x)*w1)*inv);
    o.y = f2bf((bf2f(a.y)*w0 + bf2f(c.y)*w1)*inv);
    o.z = f2bf((bf2f(a.z)*w0 + bf2f(c.z)*w1)*inv);
    o.w = f2bf((bf2f(a.w)*w0 + bf2f(c.w)*w1)*inv);
    *reinterpret_cast<short4*>(&ob[(size_t)tok*512 + dd]) = o;
}

// -------------------------------------------------------------------------------
extern "C" void kernel_launch(void* const* d_in, const int* in_sizes, int n_in,
                              void* d_out, int out_size, void* d_ws, size_t ws_size,
                              hipStream_t stream)
{
    const float* x      = (const float*)d_in[0];
    const float* coords = (const float*)d_in[1];
    const unsigned char* mask = (const unsigned char*)d_in[2];
    const float* ln1_g = (const float*)d_in[3];
    const float* ln1_b = (const float*)d_in[4];
    const float* w_qkv = (const float*)d_in[5];
    const float* b_qkv = (const float*)d_in[6];
    const float* w_edge= (const float*)d_in[7];
    const float* w_out = (const float*)d_in[8];
    const float* b_out = (const float*)d_in[9];
    const float* ln2_g = (const float*)d_in[10];
    const float* ln2_b = (const float*)d_in[11];
    const float* w1    = (const float*)d_in[12];
    const float* b1    = (const float*)d_in[13];
    const float* w2    = (const float*)d_in[14];
    const float* b2    = (const float*)d_in[15];
    float* out = (float*)d_out;

    char* W = (char*)d_ws;
    const size_t MB = 1024*1024;
    float* x1    = (float*)(W);                    // [0,4M) f32
    short* qk    = (short*)(W + 4*MB);             // [4M,8M)
    short* vtb   = (short*)(W + 8*MB);             // [8M,10M)
    short* woutT = (short*)(W + 10*MB);            // [10M,10.5M)
    short* xln   = (short*)(W + 10*MB + 512*1024); // [10.5M,12.5M)  (later y)
    short* wqkvT = (short*)(W + 12*MB + 512*1024); // [12.5M,14M)
    short* Opart = (short*)(W + 14*MB + 512*1024); // [14.5M,18.5M) bf16 2x2048x512
    float* mlp   = (float*)(W + 22*MB + 512*1024); // [22.5M,22.75M)
    unsigned long long* mb64 = (unsigned long long*)(W + 23*MB); // [23M,23.25M)
    short* ob    = (short*)(W + 6*MB);             // [6M,8M)  (qk dead after attn)
    short* y     = xln;
    short* w1T   = (short*)(W + 4*MB);             // [4M,6M)  (qk dead)
    short* w2T   = (short*)(W + 8*MB);             // [8M,10M) (vtb dead)
    short* hid   = (short*)(W + 14*MB + 512*1024); // [14.5M,22.5M) (Opart dead)

    // ---- phase 1 ----
    mask_pack<<<dim3(8192,1,1), 256, 0, stream>>>(mask, mb64);
    wconv_t<<<dim3(1536/32, 512/32), 256, 0, stream>>>(w_qkv, wqkvT, 512, 1536);
    wconv_t<<<dim3(512/32, 512/32), 256, 0, stream>>>(w_out, woutT, 512, 512);
    ln_bf16<<<MTOK, 256, 0, stream>>>(x, ln1_g, ln1_b, xln);
    gemm64<0,true,false,1,true,8><<<dim3(512,1,1), 256, 0, stream>>>(
        xln, wqkvT, b_qkv, qk, MTOK, 1024, 512, 16);
    gemm64<0,true,true,1,false,8><<<dim3(256,1,1), 256, 0, stream>>>(
        wqkvT + (size_t)1024*512, xln, b_qkv + 1024, vtb, 512, MTOK, 512, 32);
    attn_reg<<<dim3(512,1,1), 256, 0, stream>>>(qk, vtb, coords, mb64, w_edge, Opart, mlp);
    attn_combine<<<dim3(1024,1,1), 256, 0, stream>>>(Opart, mlp, ob);
    addbias_f32<<<1024, 256, 0, stream>>>(x, b_out, x1);
    gemm64<3,false,false,2,false,4><<<dim3(256,1,2), 256, 0, stream>>>(
        ob, woutT, nullptr, x1, MTOK, 512, 512, 8);
    // ---- phase 2 ----
    wconv_t<<<dim3(2048/32, 512/32), 256, 0, stream>>>(w1, w1T, 512, 2048);
    wconv_t<<<dim3(512/32, 2048/32), 256, 0, stream>>>(w2, w2T, 2048, 512);
    ln_bf16<<<MTOK, 256, 0, stream>>>(x1, ln2_g, ln2_b, y);
    gemm64<2,true,false,1,false,8><<<dim3(1024,1,1), 256, 0, stream>>>(
        y, w1T, b1, hid, MTOK, 2048, 512, 32);
    addbias_f32<<<1024, 256, 0, stream>>>(x1, b2, out);
    gemm64<3,false,false,4,false,8><<<dim3(256,1,4), 256, 0, stream>>>(
        hid, w2T, nullptr, out, MTOK, 512, 2048, 8);
}